// Round 2
// baseline (737.168 us; speedup 1.0000x reference)
//
#include <hip/hip_runtime.h>
#include <math.h>

#define NQ 12
#define MULT 3.14159253438047729f

// qubit q <-> state bit (11-q). CNOT ring, range r, sequential with updated controls.
__host__ __device__ constexpr int cnotf(int s, int r) {
    for (int q = 0; q < NQ; ++q) {
        int t = q + r; if (t >= NQ) t -= NQ;
        s ^= ((s >> (11 - q)) & 1) << (11 - t);
    }
    return s;
}

// GF(2)-linear position map: element s (12 bits) -> byte offset in 16KB float buffer.
// pos = (hi<<6) | (lo ^ hi); byte = pos*4. Guarantees conflict-free transposes.
__host__ __device__ constexpr int posb(int s) {
    int hi = (s >> 6) & 63, lo = s & 63;
    return ((hi << 6) | (lo ^ hi)) << 2;
}

// Precompute 144 Rot matrices + 6 rings x 12 posb-mapped GF(2) columns.
__global__ void vqc_prep(const float* __restrict__ th, float* __restrict__ gates,
                         int* __restrict__ ptab) {
    int idx = blockIdx.x * blockDim.x + threadIdx.x;
    if (idx < 144) {
        const float* w = th + idx * 3;
        float phi = w[0], tht = w[1], om = w[2];
        float st, ct, spo, cpo, smo, cmo;
        sincosf(0.5f * tht, &st, &ct);
        sincosf(0.5f * (phi + om), &spo, &cpo);
        sincosf(0.5f * (phi - om), &smo, &cmo);
        float* o = gates + idx * 8;
        o[0] = ct * cpo;  o[1] = -ct * spo;   // u00
        o[2] = -st * cmo; o[3] = -st * smo;   // u01
        o[4] = st * cmo;  o[5] = -st * smo;   // u10
        o[6] = ct * cpo;  o[7] = ct * spo;    // u11
    } else if (idx < 144 + 72) {
        int e = idx - 144;
        int r = e / 12 + 1, m = e % 12;
        ptab[e] = posb(cnotf(1 << m, r));
    }
}

// One 1q gate on register-bit B over 64 SoA amps. ga=(u00,u01) gb=(u10,u11).
template <int B>
__device__ __forceinline__ void apply1s(float* ax, float* ay, float4 ga, float4 gb) {
#pragma unroll
    for (int j = 0; j < 64; ++j) {
        if (j & B) continue;
        float x0r = ax[j], x0i = ay[j], x1r = ax[j | B], x1i = ay[j | B];
        ax[j]     = ga.x * x0r - ga.y * x0i + ga.z * x1r - ga.w * x1i;
        ay[j]     = ga.x * x0i + ga.y * x0r + ga.z * x1i + ga.w * x1r;
        ax[j | B] = gb.x * x0r - gb.y * x0i + gb.z * x1r - gb.w * x1i;
        ay[j | B] = gb.x * x0i + gb.y * x0r + gb.z * x1i + gb.w * x1r;
    }
}

// T1 component pass (A->B plain transpose). Compile-time Gray offsets.
__device__ __forceinline__ void tpassA(float* comp, char* sb, int wbase, int rbase) {
    int woff = 0;
#pragma unroll
    for (int st = 0; st < 64; ++st) {
        const int g = st ^ (st >> 1);
        *(float*)(sb + (wbase ^ woff)) = comp[g];
        if (st < 63) woff ^= (260 << __builtin_ctz(st + 1));  // posb(1<<(6+k))
    }
    int roff = 0;
#pragma unroll
    for (int st = 0; st < 64; ++st) {
        const int g = st ^ (st >> 1);
        comp[g] = *(const float*)(sb + (rbase ^ roff));
        if (st < 63) roff ^= (4 << __builtin_ctz(st + 1));    // posb(1<<k)
    }
}

// T2 component pass (B->A with CNOT perm folded into writes). wcols = posb(f(1<<k)).
__device__ __forceinline__ void tpassB(float* comp, char* sb, int wbase,
                                       const int* wcols, int rbase) {
    int woff = 0;
#pragma unroll
    for (int st = 0; st < 64; ++st) {
        const int g = st ^ (st >> 1);
        *(float*)(sb + (wbase ^ woff)) = comp[g];
        if (st < 63) woff ^= wcols[__builtin_ctz(st + 1)];
    }
    int roff = 0;
#pragma unroll
    for (int st = 0; st < 64; ++st) {
        const int g = st ^ (st >> 1);
        comp[g] = *(const float*)(sb + (rbase ^ roff));
        if (st < 63) roff ^= (260 << __builtin_ctz(st + 1));  // posb(1<<(6+k))
    }
}

__global__ __launch_bounds__(128, 1) void vqc_main(
        const float* __restrict__ x,
        const float* __restrict__ gates,
        const int* __restrict__ ptab,
        float* __restrict__ out, int nstates) {
    __shared__ char sbuf[32768];  // 16KB per wave, wave-private, barrier-free
    const int t = threadIdx.x;
    const int lane = t & 63;
    const int wv = t >> 6;
    const int b = blockIdx.x * 2 + wv;
    if (b >= nstates) return;
    char* sb = sbuf;  // wave offset folded into bases (bit 14, XOR-safe)

    const int wvb = wv << 14;
    const int base4L = wvb | (lane << 2);    // posb(L)
    const int base260L = wvb | (lane * 260); // posb(L<<6)

    float ax[64], ay[64];
    float myang = 0.0f;

#pragma unroll 1
    for (int l = 0; l < 2; ++l) {
        if (l == 0) myang = (lane < NQ) ? x[b * NQ + lane] : 0.0f;
        float sv, cv;
        sincosf(0.5f * myang, &sv, &cv);
        float cq[NQ], sq[NQ];
#pragma unroll
        for (int q = 0; q < NQ; ++q) {
            cq[q] = __shfl(cv, q, 64);
            sq[q] = __shfl(sv, q, 64);
        }
        // ---- product-state init: lane part x reg-bit doubling tree ----
        float pl = 1.0f;
#pragma unroll
        for (int k = 0; k < 6; ++k) pl *= ((lane >> k) & 1) ? sq[11 - k] : cq[11 - k];
        ax[0] = pl;
#pragma unroll
        for (int bb = 0; bb < 6; ++bb) {
#pragma unroll
            for (int j = 0; j < (1 << bb); ++j) {
                ax[j | (1 << bb)] = ax[j] * sq[5 - bb];
                ax[j] = ax[j] * cq[5 - bb];
            }
        }
#pragma unroll
        for (int j = 0; j < 64; ++j) ay[j] = 0.0f;

#pragma unroll 1
        for (int d = 0; d < 6; ++d) {
            // per-depth perm columns (ring r = d+1), uniform scalar loads
            int wc2[6], wbc[6];
#pragma unroll
            for (int k = 0; k < 6; ++k) {
                wc2[k] = ptab[d * 12 + k];
                wbc[k] = ptab[d * 12 + 6 + k];
            }
            int wbperm = 0;
#pragma unroll
            for (int k = 0; k < 6; ++k)
                if ((lane >> k) & 1) wbperm ^= wbc[k];
            const int wbase2 = wvb | wbperm;

#pragma unroll 1
            for (int ph = 0; ph < 2; ++ph) {
                const float4* gg =
                    (const float4*)(gates + (size_t)(((l * 6 + d) * 12) + ph * 6) * 8);
                float4 g0 = gg[0], g1 = gg[1], g2 = gg[2], g3 = gg[3];
                float4 g4 = gg[4], g5 = gg[5], g6 = gg[6], g7 = gg[7];
                float4 g8 = gg[8], g9 = gg[9], g10 = gg[10], g11 = gg[11];
                apply1s<32>(ax, ay, g0, g1);
                apply1s<16>(ax, ay, g2, g3);
                apply1s<8>(ax, ay, g4, g5);
                apply1s<4>(ax, ay, g6, g7);
                apply1s<2>(ax, ay, g8, g9);
                apply1s<1>(ax, ay, g10, g11);

                if (ph == 0) {
                    tpassA(ax, sb, base4L, base260L);
                    tpassA(ay, sb, base4L, base260L);
                } else {
                    tpassB(ax, sb, wbase2, wc2, base4L);
                    tpassB(ay, sb, wbase2, wc2, base4L);
                }
            }
        }

        // ---- readout: T + 6 reg-qubit signed sums, then wave reductions ----
        float T = 0.f, E0 = 0.f, E1 = 0.f, E2 = 0.f, E3 = 0.f, E4 = 0.f, E5 = 0.f;
#pragma unroll
        for (int j = 0; j < 64; ++j) {
            float p = ax[j] * ax[j] + ay[j] * ay[j];
            T += p;
            E0 += (j & 32) ? -p : p;  // qubit 0 <-> reg bit 5
            E1 += (j & 16) ? -p : p;
            E2 += (j & 8) ? -p : p;
            E3 += (j & 4) ? -p : p;
            E4 += (j & 2) ? -p : p;
            E5 += (j & 1) ? -p : p;
        }
#pragma unroll
        for (int m = 1; m < 64; m <<= 1) {
            E0 += __shfl_xor(E0, m, 64);
            E1 += __shfl_xor(E1, m, 64);
            E2 += __shfl_xor(E2, m, 64);
            E3 += __shfl_xor(E3, m, 64);
            E4 += __shfl_xor(E4, m, 64);
            E5 += __shfl_xor(E5, m, 64);
        }
        // Walsh-Hadamard on T: lane (1<<(11-q)) holds <Z_q> for lane-qubits 6..11
        float w = T;
#pragma unroll
        for (int m = 1; m < 64; m <<= 1) {
            float o = __shfl_xor(w, m, 64);
            w = (lane & m) ? (o - w) : (w + o);
        }
        if (l == 0) {
            float w6 = __shfl(w, 32, 64), w7 = __shfl(w, 16, 64), w8 = __shfl(w, 8, 64);
            float w9 = __shfl(w, 4, 64), w10 = __shfl(w, 2, 64), w11 = __shfl(w, 1, 64);
            myang = (lane == 0) ? E0 : (lane == 1) ? E1 : (lane == 2) ? E2 :
                    (lane == 3) ? E3 : (lane == 4) ? E4 : (lane == 5) ? E5 :
                    (lane == 6) ? w6 : (lane == 7) ? w7 : (lane == 8) ? w8 :
                    (lane == 9) ? w9 : (lane == 10) ? w10 : (lane == 11) ? w11 : 0.0f;
        } else {
            float w6 = __shfl(w, 32, 64), w7 = __shfl(w, 16, 64), w8 = __shfl(w, 8, 64);
            float v = (lane == 0) ? E3 : (lane == 1) ? E4 : (lane == 2) ? E5 :
                      (lane == 3) ? w6 : (lane == 4) ? w7 : w8;
            if (lane < 6) out[b * 6 + lane] = v * MULT;
        }
    }
}

extern "C" void kernel_launch(void* const* d_in, const int* in_sizes, int n_in,
                              void* d_out, int out_size, void* d_ws, size_t ws_size,
                              hipStream_t stream) {
    const float* x = (const float*)d_in[0];
    const float* th = (const float*)d_in[1];
    float* outp = (float*)d_out;
    float* gates = (float*)d_ws;                    // 144*8 floats = 4608 B
    int* ptab = (int*)((char*)d_ws + 4608);         // 72 ints = 288 B

    int batch = in_sizes[0] / NQ;
    int blocks = (batch + 1) / 2;

    hipLaunchKernelGGL(vqc_prep, dim3(1), dim3(256), 0, stream, th, gates, ptab);
    hipLaunchKernelGGL(vqc_main, dim3(blocks), dim3(128), 0, stream, x, gates, ptab,
                       outp, batch);
}